// Round 1
// baseline (442.678 us; speedup 1.0000x reference)
//
#include <hip/hip_runtime.h>
#include <cstdint>
#include <cstddef>

#define DI __device__ __forceinline__

typedef __attribute__((ext_vector_type(8))) short short8;
typedef __attribute__((ext_vector_type(4))) float floatx4;

static constexpr int BATCH = 16384;
static constexpr int H = 1024;

DI unsigned short f32_to_bf16_bits(float x) {
  union { float f; unsigned int u; } c; c.f = x;
  unsigned int r = c.u + 0x7fffu + ((c.u >> 16) & 1u);
  return (unsigned short)(r >> 16);
}

// ---------------- K0a: fp32 -> bf16 cast (prev), vectorized ----------------
__global__ __launch_bounds__(256) void cast_bf16_kernel(const float* __restrict__ in,
                                                        unsigned short* __restrict__ out) {
  const int i = (blockIdx.x * 256 + threadIdx.x) * 4;
  const float4 v = *reinterpret_cast<const float4*>(in + i);
  ushort4 o;
  o.x = f32_to_bf16_bits(v.x);
  o.y = f32_to_bf16_bits(v.y);
  o.z = f32_to_bf16_bits(v.z);
  o.w = f32_to_bf16_bits(v.w);
  *reinterpret_cast<ushort4*>(out + i) = o;
}

// ------------- K0b/c: transpose + cast: out[n][k] = in[k][col0 + n] --------
// in: H x src_stride fp32; out: H x H bf16 (N-major, k contiguous)
__global__ __launch_bounds__(256) void transpose_cast_kernel(const float* __restrict__ in,
                                                             unsigned short* __restrict__ out,
                                                             int src_stride, int src_col0) {
  __shared__ float tile[32][33];
  const int bx = blockIdx.x * 32;  // k (input row)
  const int by = blockIdx.y * 32;  // n (input col)
  const int tx = threadIdx.x;      // 0..31
  const int ty = threadIdx.y;      // 0..7
#pragma unroll
  for (int i = 0; i < 32; i += 8)
    tile[ty + i][tx] = in[(size_t)(bx + ty + i) * src_stride + src_col0 + by + tx];
  __syncthreads();
#pragma unroll
  for (int i = 0; i < 32; i += 8)
    out[(size_t)(by + ty + i) * H + bx + tx] = f32_to_bf16_bits(tile[tx][ty + i]);
}

// ---------------- fused MFMA GEMM: C = A(MxK) @ Bt(NxK)^T ------------------
// EPI 0: reset-gate epilogue -> X bf16.  EPI 1: tanh/mask epilogue -> out f32.
template <int EPI>
__global__ __launch_bounds__(256, 2) void gemm_fused(const unsigned short* __restrict__ A,
                                                     const unsigned short* __restrict__ Bt,
                                                     const float* __restrict__ inp,
                                                     const float* __restrict__ prev,
                                                     const float* __restrict__ mask,
                                                     unsigned short* __restrict__ Xout,
                                                     float* __restrict__ Out) {
  // Tiles: BM=128, BN=128, BK=64. LDS: two 128x64 bf16 tiles (16 KB each).
  __shared__ __align__(16) unsigned short ldsA[128 * 64];
  __shared__ __align__(16) unsigned short ldsB[128 * 64];

  const int tid = threadIdx.x;
  const int lane = tid & 63;
  const int wave = tid >> 6;
  const int wm = wave >> 1;       // wave row quadrant (0..1)
  const int wn = wave & 1;        // wave col quadrant (0..1)
  const int q = lane >> 4;        // quad 0..3
  const int l16 = lane & 15;
  const int blockM = blockIdx.y * 128;
  const int blockN = blockIdx.x * 128;

  floatx4 acc[4][4] = {};

  for (int kt = 0; kt < H; kt += 64) {
    // ---- stage A,B tiles: 1024 chunks each of 16B; chunk c -> row r=c>>3,
    // phys chunk pc=c&7 holds logical chunk pc^(r&7) (XOR swizzle so the
    // fragment ds_read_b128s spread over all 8 bank groups: 2-way = free).
#pragma unroll
    for (int j = 0; j < 4; ++j) {
      const int c = j * 256 + tid;
      const int r = c >> 3;
      const int gc = (c & 7) ^ (r & 7);
      const int cb = j * 256 + (wave << 6);  // wave-uniform chunk base
      const unsigned short* srcA = A + (size_t)(blockM + r) * H + kt + gc * 8;
      const unsigned short* srcB = Bt + (size_t)(blockN + r) * H + kt + gc * 8;
#if __has_builtin(__builtin_amdgcn_global_load_lds)
      __builtin_amdgcn_global_load_lds(
          (const __attribute__((address_space(1))) unsigned int*)srcA,
          (__attribute__((address_space(3))) unsigned int*)(&ldsA[cb * 8]), 16, 0, 0);
      __builtin_amdgcn_global_load_lds(
          (const __attribute__((address_space(1))) unsigned int*)srcB,
          (__attribute__((address_space(3))) unsigned int*)(&ldsB[cb * 8]), 16, 0, 0);
#else
      *(short8*)&ldsA[c * 8] = *(const short8*)srcA;
      *(short8*)&ldsB[c * 8] = *(const short8*)srcB;
#endif
    }
#if __has_builtin(__builtin_amdgcn_global_load_lds)
    asm volatile("s_waitcnt vmcnt(0)" ::: "memory");
#endif
    __syncthreads();

    // ---- compute: 2 k-steps of 32, 16 MFMAs each
#pragma unroll
    for (int ks = 0; ks < 2; ++ks) {
      short8 af[4], bfr[4];
#pragma unroll
      for (int i = 0; i < 4; ++i) {
        const int r = wm * 64 + i * 16 + l16;
        const int ch = ks * 4 + q;
        af[i] = *(const short8*)&ldsA[(r * 8 + (ch ^ (r & 7))) * 8];
      }
#pragma unroll
      for (int j = 0; j < 4; ++j) {
        const int r = wn * 64 + j * 16 + l16;
        const int ch = ks * 4 + q;
        bfr[j] = *(const short8*)&ldsB[(r * 8 + (ch ^ (r & 7))) * 8];
      }
#pragma unroll
      for (int i = 0; i < 4; ++i)
#pragma unroll
        for (int j = 0; j < 4; ++j)
          acc[i][j] = __builtin_amdgcn_mfma_f32_16x16x32_bf16(af[i], bfr[j], acc[i][j], 0, 0, 0);
    }
    __syncthreads();
  }

  // ---- epilogue. C/D map: col = lane&15, row = quad*4 + reg (verified m89/m91)
#pragma unroll
  for (int i = 0; i < 4; ++i) {
    const int gr0 = blockM + wm * 64 + i * 16 + q * 4;
#pragma unroll
    for (int j = 0; j < 4; ++j) {
      const int gcol = blockN + wn * 64 + j * 16 + l16;
#pragma unroll
      for (int rg = 0; rg < 4; ++rg) {
        const int gr = gr0 + rg;
        const float v = acc[i][j][rg];
        if (EPI == 0) {
          // reset = sigmoid(G + gate_r); X = state_inp * reset
          const float z = v + inp[(size_t)gr * (3 * H) + 2 * H + gcol];
          const float rst = 1.0f / (1.0f + __expf(-z));
          const float x = inp[(size_t)gr * (3 * H) + gcol] * rst;
          Xout[(size_t)gr * H + gcol] = f32_to_bf16_bits(x);
        } else {
          // out = mask*(tanh(P + s) + 1) + prev   [update cancels; expanded mask form]
          const float s = inp[(size_t)gr * (3 * H) + gcol];
          const float a = v + s;
          const float ns = 1.0f - 2.0f / (__expf(2.0f * a) + 1.0f);  // tanh, overflow-safe
          const float m = mask[gr];
          Out[(size_t)gr * H + gcol] = m * (ns + 1.0f) + prev[(size_t)gr * H + gcol];
        }
      }
    }
  }
}

extern "C" void kernel_launch(void* const* d_in, const int* in_sizes, int n_in,
                              void* d_out, int out_size, void* d_ws, size_t ws_size,
                              hipStream_t stream) {
  const float* inp = (const float*)d_in[0];    // (B, 3H)
  const float* prev = (const float*)d_in[1];   // (B, H)
  const float* mask = (const float*)d_in[2];   // (B,)
  const float* Wur = (const float*)d_in[3];    // (H, 2H)
  const float* U = (const float*)d_in[4];      // (H, H)
  float* out = (float*)d_out;

  // workspace layout
  char* ws = (char*)d_ws;
  unsigned short* prevb = (unsigned short*)ws;                          // B*H bf16 (32 MB)
  unsigned short* Xb = (unsigned short*)(ws + (size_t)BATCH * H * 2);   // B*H bf16 (32 MB)
  unsigned short* WrT = (unsigned short*)(ws + (size_t)BATCH * H * 4);  // H*H bf16 (2 MB)
  unsigned short* UT = WrT + (size_t)H * H;                             // H*H bf16 (2 MB)

  // K0: casts / transposes
  cast_bf16_kernel<<<(BATCH * H) / (256 * 4), 256, 0, stream>>>(prev, prevb);
  transpose_cast_kernel<<<dim3(H / 32, H / 32), dim3(32, 8), 0, stream>>>(Wur, WrT, 2 * H, H);
  transpose_cast_kernel<<<dim3(H / 32, H / 32), dim3(32, 8), 0, stream>>>(U, UT, H, 0);

  // K1: G = prev@Wr -> reset -> X (bf16)
  gemm_fused<0><<<dim3(H / 128, BATCH / 128), 256, 0, stream>>>(prevb, WrT, inp, nullptr,
                                                                nullptr, Xb, nullptr);
  // K2: P = X@U -> out
  gemm_fused<1><<<dim3(H / 128, BATCH / 128), 256, 0, stream>>>(Xb, UT, inp, prev, mask,
                                                                nullptr, out);
}